// Round 18
// baseline (103.275 us; speedup 1.0000x reference)
//
#include <hip/hip_runtime.h>
#include <math.h>

// local_mixer via bf16 MFMA. R18 = R12 (98.8us champion) + deferred softmax
// normalization: pack UNNORMALIZED E right after exp2 (chain: exp2 -> cvt_pk
// -> sP -> PV); the 31-add tree + shfl_xor(~120cy ds_bpermute) + rcp run OFF
// the pack->PV critical path, iv parked in a 1KB per-wave LDS array and
// folded into the store post-PV (O = (E·V) * iv[i], algebraically identical).
// Everything else byte-identical to R12.
//   x:[8,256,256,64]f32  W:[192,64]f32  b:[192]f32  pos:[1,8,64,64]f32
//   out:[8192,64,64]f32

typedef __attribute__((ext_vector_type(8)))  short bf16x8;
typedef __attribute__((ext_vector_type(4)))  float f32x4;
typedef __attribute__((ext_vector_type(16))) float f32x16;

__device__ inline unsigned int cvt_pk_bf16(float lo, float hi) {
    unsigned int r;
    asm("v_cvt_pk_bf16_f32 %0, %1, %2" : "=v"(r) : "v"(lo), "v"(hi));
    return r;
}
__device__ inline unsigned short f2bf(float f) {   // prep kernel only
    unsigned int u = __builtin_bit_cast(unsigned int, f);
    return (unsigned short)((u + 0x7FFFu + ((u >> 16) & 1u)) >> 16);
}
#define BFLO(u) __builtin_bit_cast(float, (unsigned int)((u) << 16))
#define BFHI(u) __builtin_bit_cast(float, (unsigned int)((u) & 0xffff0000u))

__device__ inline bf16x8 pack8(float4 a, float4 b) {
    union { unsigned int u[4]; bf16x8 v; } r;
    r.u[0] = cvt_pk_bf16(a.x, a.y);
    r.u[1] = cvt_pk_bf16(a.z, a.w);
    r.u[2] = cvt_pk_bf16(b.x, b.y);
    r.u[3] = cvt_pk_bf16(b.z, b.w);
    return r.v;
}

// ---- prep: pos^T fragments (32x32 C layout of S^T tiles), *log2e, bf16 ----
// flat = (((h*2 + it)*2 + jt)*64 + lane)*16 + reg
__global__ __launch_bounds__(256) void prep_pos(const float* __restrict__ pos,
                                                unsigned short* __restrict__ pp)
{
    int flat = blockIdx.x * 256 + threadIdx.x;   // 0..32767
    int r  = flat & 15;
    int ln = (flat >> 4) & 63;
    int jt = (flat >> 10) & 1;
    int it = (flat >> 11) & 1;
    int h  = flat >> 12;
    int j = jt*32 + (r & 3) + 8*(r >> 2) + 4*(ln >> 5);   // S^T row
    int i = it*32 + (ln & 31);                            // S^T col
    pp[flat] = f2bf(pos[(h*64 + i)*64 + j] * 1.4426950408889634f);
}

__global__ __launch_bounds__(256, 3) void lm_mfma(const float* __restrict__ x,
                                                  const float* __restrict__ Wq,
                                                  const float* __restrict__ bq,
                                                  const unsigned short* __restrict__ pp,
                                                  float* __restrict__ out)
{
    // 41 KB LDS. Chunk-swizzle: 8-bf16 chunk c8 of row r at c8^(r&7).
    __shared__ unsigned short sPool[4*32*64];  // 16 KB: sX (8 KB) then sP (16 KB)
    __shared__ unsigned short sQ [64*64];      // q (scaled*log2e) [i][d]
    __shared__ unsigned short sK [64*64];      // k [j][d]
    __shared__ unsigned short sVT[64*64];      // v^T [c][j]
    __shared__ float sIv[4*64];                // per-wave iv[i] (deferred norm)
    unsigned short* const sX = sPool;
    unsigned short* const sP = sPool;

    const int tid = threadIdx.x;
    const int w   = blockIdx.x;
    const int ln  = tid & 63;
    const int wv  = tid >> 6;
    const int lr  = ln & 15;
    const int lg  = ln >> 4;

    const int bi = w >> 10, mm = w & 1023;
    const int mh = mm >> 5, mw = mm & 31;
    const float* xwin = x + ((size_t)(bi*256 + mh*8)*256 + mw*8)*64;

    // ---- stage x -> sX (bf16, swizzled) ----
    #pragma unroll
    for (int r = 0; r < 4; ++r) {
        const int f4 = tid + r*256;
        const int n  = f4 >> 4;
        const int c  = (f4 & 15) * 4;
        const float4 v = *(const float4*)(xwin + ((size_t)(n>>3)*256 + (n&7))*64 + c);
        uint2 u;
        u.x = cvt_pk_bf16(v.x, v.y);
        u.y = cvt_pk_bf16(v.z, v.w);
        *(uint2*)&sX[n*64 + (((c>>3) ^ (n&7))<<3) + (c&7)] = u;
    }

    // ---- W fragments: wave wv owns d-tiles {wv, wv+4, wv+8} ----
    bf16x8 wfrag[3][2];
    #pragma unroll
    for (int t = 0; t < 3; ++t) {
        const int d = (wv + 4*t)*16 + lr;
        #pragma unroll
        for (int kt = 0; kt < 2; ++kt) {
            const float* base = Wq + (size_t)d*64 + kt*32 + lg*8;
            wfrag[t][kt] = pack8(*(const float4*)base, *(const float4*)(base+4));
        }
    }
    const float qs = 0.35355339059327373f * 1.4426950408889634f;  // 8^-0.5 * log2e
    const float4 bqQr = *(const float4*)(bq       + wv*16 + lg*4);
    const float4 bqK  = *(const float4*)(bq + 64  + wv*16 + lg*4);
    const float  bqV  = bq[128 + wv*16 + lr];
    float4 bqQs;
    bqQs.x = bqQr.x*qs; bqQs.y = bqQr.y*qs; bqQs.z = bqQr.z*qs; bqQs.w = bqQr.w*qs;

    __syncthreads();

    // ---- QKV MFMAs (16x16x32, single pass) ----
    f32x4 aQ[4], aK[4], aV[4];
    #pragma unroll
    for (int nt = 0; nt < 4; ++nt) { aQ[nt]=0; aK[nt]=0; aV[nt]=0; }

    #pragma unroll
    for (int nt = 0; nt < 4; ++nt) {
        #pragma unroll
        for (int kt = 0; kt < 2; ++kt) {
            const int n  = lr + nt*16;
            const int c8 = lg + kt*4;
            const bf16x8 xf = *(const bf16x8*)&sX[n*64 + ((c8 ^ (n&7))<<3)];
            aQ[nt] = __builtin_amdgcn_mfma_f32_16x16x32_bf16(wfrag[0][kt], xf, aQ[nt], 0,0,0);
            aK[nt] = __builtin_amdgcn_mfma_f32_16x16x32_bf16(wfrag[1][kt], xf, aK[nt], 0,0,0);
            aV[nt] = __builtin_amdgcn_mfma_f32_16x16x32_bf16(xf, wfrag[2][kt], aV[nt], 0,0,0);
        }
    }

    #pragma unroll
    for (int nt = 0; nt < 4; ++nt) {
        const int n  = lr + nt*16;
        const int d0 = wv*16 + lg*4;
        const int qidx = n*64 + (((d0>>3) ^ (n&7))<<3) + (d0&7);
        uint2 uq, uk;
        uq.x = cvt_pk_bf16(fmaf(aQ[nt][0], qs, bqQs.x), fmaf(aQ[nt][1], qs, bqQs.y));
        uq.y = cvt_pk_bf16(fmaf(aQ[nt][2], qs, bqQs.z), fmaf(aQ[nt][3], qs, bqQs.w));
        uk.x = cvt_pk_bf16(aK[nt][0]+bqK.x, aK[nt][1]+bqK.y);
        uk.y = cvt_pk_bf16(aK[nt][2]+bqK.z, aK[nt][3]+bqK.w);
        *(uint2*)&sQ[qidx] = uq;
        *(uint2*)&sK[qidx] = uk;
        const int cc = wv*16 + lr;
        const int n0 = nt*16 + lg*4;
        uint2 uv;
        uv.x = cvt_pk_bf16(aV[nt][0]+bqV, aV[nt][1]+bqV);
        uv.y = cvt_pk_bf16(aV[nt][2]+bqV, aV[nt][3]+bqV);
        *(uint2*)&sVT[cc*64 + (((n0>>3) ^ (cc&7))<<3) + (n0&7)] = uv;
    }

    __syncthreads();

    // ---- attention: wave wv -> heads {2wv, 2wv+1}; it-pair pipelined ----
    unsigned short* const pw = sP + ((wv*32 + (ln & 31)) << 6);  // this lane's P row
    const int il  = ln & 31;
    const int hi4 = (ln >> 5) * 4;

    #pragma unroll 1
    for (int hh = 0; hh < 2; ++hh) {
        const int h = wv*2 + hh;

        // V^T B-frags for 16x16 PV (cols 8..15 zero), shared by both i-tiles
        bf16x8 vf[2];
        #pragma unroll
        for (int kt = 0; kt < 2; ++kt) {
            bf16x8 z = {};
            vf[kt] = z;
            if (lr < 8) {
                const int cc = h*8 + lr;
                const int j0 = kt*32 + lg*8;
                vf[kt] = *(const bf16x8*)&sVT[cc*64 + (((j0>>3) ^ (cc&7))<<3)];
            }
        }

        // C-init = pos^T fragments (bf16, *log2e, pre-permuted), both i-tiles
        f32x16 C[2][2];
        #pragma unroll
        for (int it = 0; it < 2; ++it)
            #pragma unroll
            for (int jt = 0; jt < 2; ++jt) {
                const unsigned short* pb = pp + (((h*2+it)*2 + jt)*64 + ln)*16;
                const uint4 a = *(const uint4*)(pb);
                const uint4 b = *(const uint4*)(pb + 8);
                C[it][jt][0]=BFLO(a.x);  C[it][jt][1]=BFHI(a.x);
                C[it][jt][2]=BFLO(a.y);  C[it][jt][3]=BFHI(a.y);
                C[it][jt][4]=BFLO(a.z);  C[it][jt][5]=BFHI(a.z);
                C[it][jt][6]=BFLO(a.w);  C[it][jt][7]=BFHI(a.w);
                C[it][jt][8]=BFLO(b.x);  C[it][jt][9]=BFHI(b.x);
                C[it][jt][10]=BFLO(b.y); C[it][jt][11]=BFHI(b.y);
                C[it][jt][12]=BFLO(b.z); C[it][jt][13]=BFHI(b.z);
                C[it][jt][14]=BFLO(b.w); C[it][jt][15]=BFHI(b.w);
            }

        // swapped QK^T: S^T = K·Q^T (32x32x16, K=8 of 16). kf shared by both i-tiles.
        bf16x8 qf0 = {}, qf1 = {}, kf0 = {}, kf1 = {};
        if (ln < 32) {
            qf0 = *(const bf16x8*)&sQ[ln*64 + ((h ^ (ln&7))<<3)];
            const int i1 = 32 + ln;
            qf1 = *(const bf16x8*)&sQ[i1*64 + ((h ^ (i1&7))<<3)];
            kf0 = *(const bf16x8*)&sK[ln*64 + ((h ^ (ln&7))<<3)];
            kf1 = *(const bf16x8*)&sK[i1*64 + ((h ^ (i1&7))<<3)];
        }
        C[0][0] = __builtin_amdgcn_mfma_f32_32x32x16_bf16(kf0, qf0, C[0][0], 0,0,0);
        C[0][1] = __builtin_amdgcn_mfma_f32_32x32x16_bf16(kf1, qf0, C[0][1], 0,0,0);
        C[1][0] = __builtin_amdgcn_mfma_f32_32x32x16_bf16(kf0, qf1, C[1][0], 0,0,0);
        C[1][1] = __builtin_amdgcn_mfma_f32_32x32x16_bf16(kf1, qf1, C[1][1], 0,0,0);

        // per i-tile: exp2 -> pack UNNORMALIZED E -> sP -> PV. Sum tree +
        // shfl + rcp run off the chain; iv parked in sIv for post-PV use.
        f32x4 O[2][2];
        #pragma unroll
        for (int it = 0; it < 2; ++it) {
            #pragma unroll
            for (int jt = 0; jt < 2; ++jt)
                #pragma unroll
                for (int e = 0; e < 16; ++e)
                    C[it][jt][e] = __builtin_amdgcn_exp2f(C[it][jt][e]);

            // pack unnormalized E pairs -> this lane's sP row (R12 swizzle)
            #pragma unroll
            for (int jt = 0; jt < 2; ++jt)
                #pragma unroll
                for (int G = 0; G < 4; ++G) {
                    uint2 u;
                    u.x = cvt_pk_bf16(C[it][jt][4*G+0], C[it][jt][4*G+1]);
                    u.y = cvt_pk_bf16(C[it][jt][4*G+2], C[it][jt][4*G+3]);
                    const int j0 = jt*32 + 8*G + hi4;
                    *(uint2*)&pw[(((j0>>3) ^ (il&7))<<3) + (j0&7)] = u;
                }

            // row-sum (off the pack->PV critical path)
            float t[8];
            #pragma unroll
            for (int jt = 0; jt < 2; ++jt)
                #pragma unroll
                for (int g = 0; g < 4; ++g) {
                    const int b = g*4;
                    t[jt*4+g] = (C[it][jt][b+0]+C[it][jt][b+1])
                              + (C[it][jt][b+2]+C[it][jt][b+3]);
                }
            const float sum = ((t[0]+t[1])+(t[2]+t[3])) + ((t[4]+t[5])+(t[6]+t[7]));
            const float tot = sum + __shfl_xor(sum, 32, 64);
            if (ln < 32)
                sIv[wv*64 + it*32 + il] = __builtin_amdgcn_rcpf(tot);

            // PV: 16x16x32, A = E rows (b128), B = vf. Two independent chains.
            O[it][0] = 0; O[it][1] = 0;
            #pragma unroll
            for (int pit = 0; pit < 2; ++pit)
                #pragma unroll
                for (int kt = 0; kt < 2; ++kt) {
                    const int i = pit*16 + lr;
                    const bf16x8 pf = *(const bf16x8*)&sP[(wv*32+i)*64
                                      + (((kt*4+lg) ^ (i&7))<<3)];
                    O[it][pit] = __builtin_amdgcn_mfma_f32_16x16x32_bf16(pf, vf[kt],
                                                                         O[it][pit], 0,0,0);
                }
        }

        // stores: lane col c = lr (<8), rows i = it*32 + pit*16 + lg*4 + r.
        // normalize with iv from sIv (b128 broadcast read per (it,pit)).
        if (lr < 8) {
            #pragma unroll
            for (int it = 0; it < 2; ++it)
                #pragma unroll
                for (int pit = 0; pit < 2; ++pit) {
                    const float4 ivv = *(const float4*)&sIv[wv*64 + it*32
                                                            + pit*16 + lg*4];
                    float* ob = out + (size_t)w*4096
                              + (size_t)(it*32 + pit*16 + lg*4)*64 + h*8 + lr;
                    ob[0]   = O[it][pit][0] * ivv.x;
                    ob[64]  = O[it][pit][1] * ivv.y;
                    ob[128] = O[it][pit][2] * ivv.z;
                    ob[192] = O[it][pit][3] * ivv.w;
                }
        }
    }
}

extern "C" void kernel_launch(void* const* d_in, const int* in_sizes, int n_in,
                              void* d_out, int out_size, void* d_ws, size_t ws_size,
                              hipStream_t stream)
{
    const float* x   = (const float*)d_in[0];
    const float* Wq  = (const float*)d_in[1];
    const float* bq  = (const float*)d_in[2];
    const float* pos = (const float*)d_in[3];
    float* out = (float*)d_out;
    unsigned short* pp = (unsigned short*)d_ws;   // 64 KB

    hipLaunchKernelGGL(prep_pos, dim3(128), dim3(256), 0, stream, pos, pp);
    hipLaunchKernelGGL(lm_mfma, dim3(8192), dim3(256), 0, stream, x, Wq, bq, pp, out);
}

// Round 19
// 97.727 us; speedup vs baseline: 1.0568x; 1.0568x over previous
//
#include <hip/hip_runtime.h>
#include <math.h>

// local_mixer via bf16 MFMA. R19 = R12 (98.8us champion) with the register
// live-set cut below the 128-reg/wave line to unlock 4 waves/SIMD (from 3):
// (1) each it-unit's O is stored to global immediately after its PV (O acc
// live-set 16->8), (2) __launch_bounds__(256,4). Unified-file audit: QKV
// phase ~98 regs, attention phase ~112 regs -> no spill expected (verify via
// WRITE_SIZE). Everything else byte-identical to R12.
//   x:[8,256,256,64]f32  W:[192,64]f32  b:[192]f32  pos:[1,8,64,64]f32
//   out:[8192,64,64]f32

typedef __attribute__((ext_vector_type(8)))  short bf16x8;
typedef __attribute__((ext_vector_type(4)))  float f32x4;
typedef __attribute__((ext_vector_type(16))) float f32x16;

__device__ inline unsigned int cvt_pk_bf16(float lo, float hi) {
    unsigned int r;
    asm("v_cvt_pk_bf16_f32 %0, %1, %2" : "=v"(r) : "v"(lo), "v"(hi));
    return r;
}
__device__ inline unsigned short f2bf(float f) {   // prep kernel only
    unsigned int u = __builtin_bit_cast(unsigned int, f);
    return (unsigned short)((u + 0x7FFFu + ((u >> 16) & 1u)) >> 16);
}
#define BFLO(u) __builtin_bit_cast(float, (unsigned int)((u) << 16))
#define BFHI(u) __builtin_bit_cast(float, (unsigned int)((u) & 0xffff0000u))

__device__ inline bf16x8 pack8(float4 a, float4 b) {
    union { unsigned int u[4]; bf16x8 v; } r;
    r.u[0] = cvt_pk_bf16(a.x, a.y);
    r.u[1] = cvt_pk_bf16(a.z, a.w);
    r.u[2] = cvt_pk_bf16(b.x, b.y);
    r.u[3] = cvt_pk_bf16(b.z, b.w);
    return r.v;
}

// ---- prep: pos^T fragments (32x32 C layout of S^T tiles), *log2e, bf16 ----
// flat = (((h*2 + it)*2 + jt)*64 + lane)*16 + reg
__global__ __launch_bounds__(256) void prep_pos(const float* __restrict__ pos,
                                                unsigned short* __restrict__ pp)
{
    int flat = blockIdx.x * 256 + threadIdx.x;   // 0..32767
    int r  = flat & 15;
    int ln = (flat >> 4) & 63;
    int jt = (flat >> 10) & 1;
    int it = (flat >> 11) & 1;
    int h  = flat >> 12;
    int j = jt*32 + (r & 3) + 8*(r >> 2) + 4*(ln >> 5);   // S^T row
    int i = it*32 + (ln & 31);                            // S^T col
    pp[flat] = f2bf(pos[(h*64 + i)*64 + j] * 1.4426950408889634f);
}

__global__ __launch_bounds__(256, 4) void lm_mfma(const float* __restrict__ x,
                                                  const float* __restrict__ Wq,
                                                  const float* __restrict__ bq,
                                                  const unsigned short* __restrict__ pp,
                                                  float* __restrict__ out)
{
    // 40 KB LDS. Chunk-swizzle: 8-bf16 chunk c8 of row r at c8^(r&7).
    __shared__ unsigned short sPool[4*32*64];  // 16 KB: sX (8 KB) then sP (16 KB)
    __shared__ unsigned short sQ [64*64];      // q (scaled*log2e) [i][d]
    __shared__ unsigned short sK [64*64];      // k [j][d]
    __shared__ unsigned short sVT[64*64];      // v^T [c][j]
    unsigned short* const sX = sPool;
    unsigned short* const sP = sPool;

    const int tid = threadIdx.x;
    const int w   = blockIdx.x;
    const int ln  = tid & 63;
    const int wv  = tid >> 6;
    const int lr  = ln & 15;
    const int lg  = ln >> 4;

    const int bi = w >> 10, mm = w & 1023;
    const int mh = mm >> 5, mw = mm & 31;
    const float* xwin = x + ((size_t)(bi*256 + mh*8)*256 + mw*8)*64;

    // ---- stage x -> sX (bf16, swizzled) ----
    #pragma unroll
    for (int r = 0; r < 4; ++r) {
        const int f4 = tid + r*256;
        const int n  = f4 >> 4;
        const int c  = (f4 & 15) * 4;
        const float4 v = *(const float4*)(xwin + ((size_t)(n>>3)*256 + (n&7))*64 + c);
        uint2 u;
        u.x = cvt_pk_bf16(v.x, v.y);
        u.y = cvt_pk_bf16(v.z, v.w);
        *(uint2*)&sX[n*64 + (((c>>3) ^ (n&7))<<3) + (c&7)] = u;
    }

    // ---- W fragments: wave wv owns d-tiles {wv, wv+4, wv+8} ----
    bf16x8 wfrag[3][2];
    #pragma unroll
    for (int t = 0; t < 3; ++t) {
        const int d = (wv + 4*t)*16 + lr;
        #pragma unroll
        for (int kt = 0; kt < 2; ++kt) {
            const float* base = Wq + (size_t)d*64 + kt*32 + lg*8;
            wfrag[t][kt] = pack8(*(const float4*)base, *(const float4*)(base+4));
        }
    }
    const float qs = 0.35355339059327373f * 1.4426950408889634f;  // 8^-0.5 * log2e
    const float4 bqQr = *(const float4*)(bq       + wv*16 + lg*4);
    const float4 bqK  = *(const float4*)(bq + 64  + wv*16 + lg*4);
    const float  bqV  = bq[128 + wv*16 + lr];
    float4 bqQs;
    bqQs.x = bqQr.x*qs; bqQs.y = bqQr.y*qs; bqQs.z = bqQr.z*qs; bqQs.w = bqQr.w*qs;

    __syncthreads();

    // ---- QKV MFMAs (16x16x32, single pass) ----
    f32x4 aQ[4], aK[4], aV[4];
    #pragma unroll
    for (int nt = 0; nt < 4; ++nt) { aQ[nt]=0; aK[nt]=0; aV[nt]=0; }

    #pragma unroll
    for (int nt = 0; nt < 4; ++nt) {
        #pragma unroll
        for (int kt = 0; kt < 2; ++kt) {
            const int n  = lr + nt*16;
            const int c8 = lg + kt*4;
            const bf16x8 xf = *(const bf16x8*)&sX[n*64 + ((c8 ^ (n&7))<<3)];
            aQ[nt] = __builtin_amdgcn_mfma_f32_16x16x32_bf16(wfrag[0][kt], xf, aQ[nt], 0,0,0);
            aK[nt] = __builtin_amdgcn_mfma_f32_16x16x32_bf16(wfrag[1][kt], xf, aK[nt], 0,0,0);
            aV[nt] = __builtin_amdgcn_mfma_f32_16x16x32_bf16(xf, wfrag[2][kt], aV[nt], 0,0,0);
        }
    }

    #pragma unroll
    for (int nt = 0; nt < 4; ++nt) {
        const int n  = lr + nt*16;
        const int d0 = wv*16 + lg*4;
        const int qidx = n*64 + (((d0>>3) ^ (n&7))<<3) + (d0&7);
        uint2 uq, uk;
        uq.x = cvt_pk_bf16(fmaf(aQ[nt][0], qs, bqQs.x), fmaf(aQ[nt][1], qs, bqQs.y));
        uq.y = cvt_pk_bf16(fmaf(aQ[nt][2], qs, bqQs.z), fmaf(aQ[nt][3], qs, bqQs.w));
        uk.x = cvt_pk_bf16(aK[nt][0]+bqK.x, aK[nt][1]+bqK.y);
        uk.y = cvt_pk_bf16(aK[nt][2]+bqK.z, aK[nt][3]+bqK.w);
        *(uint2*)&sQ[qidx] = uq;
        *(uint2*)&sK[qidx] = uk;
        const int cc = wv*16 + lr;
        const int n0 = nt*16 + lg*4;
        uint2 uv;
        uv.x = cvt_pk_bf16(aV[nt][0]+bqV, aV[nt][1]+bqV);
        uv.y = cvt_pk_bf16(aV[nt][2]+bqV, aV[nt][3]+bqV);
        *(uint2*)&sVT[cc*64 + (((n0>>3) ^ (cc&7))<<3) + (n0&7)] = uv;
    }

    __syncthreads();

    // ---- attention: wave wv -> heads {2wv, 2wv+1}; it-pair pipelined ----
    unsigned short* const pw = sP + ((wv*32 + (ln & 31)) << 6);  // this lane's P row
    const int il  = ln & 31;
    const int hi4 = (ln >> 5) * 4;

    #pragma unroll 1
    for (int hh = 0; hh < 2; ++hh) {
        const int h = wv*2 + hh;

        // V^T B-frags for 16x16 PV (cols 8..15 zero), shared by both i-tiles
        bf16x8 vf[2];
        #pragma unroll
        for (int kt = 0; kt < 2; ++kt) {
            bf16x8 z = {};
            vf[kt] = z;
            if (lr < 8) {
                const int cc = h*8 + lr;
                const int j0 = kt*32 + lg*8;
                vf[kt] = *(const bf16x8*)&sVT[cc*64 + (((j0>>3) ^ (cc&7))<<3)];
            }
        }

        // C-init = pos^T fragments (bf16, *log2e, pre-permuted), both i-tiles
        f32x16 C[2][2];
        #pragma unroll
        for (int it = 0; it < 2; ++it)
            #pragma unroll
            for (int jt = 0; jt < 2; ++jt) {
                const unsigned short* pb = pp + (((h*2+it)*2 + jt)*64 + ln)*16;
                const uint4 a = *(const uint4*)(pb);
                const uint4 b = *(const uint4*)(pb + 8);
                C[it][jt][0]=BFLO(a.x);  C[it][jt][1]=BFHI(a.x);
                C[it][jt][2]=BFLO(a.y);  C[it][jt][3]=BFHI(a.y);
                C[it][jt][4]=BFLO(a.z);  C[it][jt][5]=BFHI(a.z);
                C[it][jt][6]=BFLO(a.w);  C[it][jt][7]=BFHI(a.w);
                C[it][jt][8]=BFLO(b.x);  C[it][jt][9]=BFHI(b.x);
                C[it][jt][10]=BFLO(b.y); C[it][jt][11]=BFHI(b.y);
                C[it][jt][12]=BFLO(b.z); C[it][jt][13]=BFHI(b.z);
                C[it][jt][14]=BFLO(b.w); C[it][jt][15]=BFHI(b.w);
            }

        // swapped QK^T: S^T = K·Q^T (32x32x16, K=8 of 16). kf shared by both i-tiles.
        bf16x8 qf0 = {}, qf1 = {}, kf0 = {}, kf1 = {};
        if (ln < 32) {
            qf0 = *(const bf16x8*)&sQ[ln*64 + ((h ^ (ln&7))<<3)];
            const int i1 = 32 + ln;
            qf1 = *(const bf16x8*)&sQ[i1*64 + ((h ^ (i1&7))<<3)];
            kf0 = *(const bf16x8*)&sK[ln*64 + ((h ^ (ln&7))<<3)];
            kf1 = *(const bf16x8*)&sK[i1*64 + ((h ^ (i1&7))<<3)];
        }
        C[0][0] = __builtin_amdgcn_mfma_f32_32x32x16_bf16(kf0, qf0, C[0][0], 0,0,0);
        C[0][1] = __builtin_amdgcn_mfma_f32_32x32x16_bf16(kf1, qf0, C[0][1], 0,0,0);
        C[1][0] = __builtin_amdgcn_mfma_f32_32x32x16_bf16(kf0, qf1, C[1][0], 0,0,0);
        C[1][1] = __builtin_amdgcn_mfma_f32_32x32x16_bf16(kf1, qf1, C[1][1], 0,0,0);

        // per i-tile: exp2 -> lane-local sum -> normalized pack -> sP -> PV ->
        // immediate store (O live-set halved vs R12; stores are fire-and-forget).
        #pragma unroll
        for (int it = 0; it < 2; ++it) {
            float t[8];
            #pragma unroll
            for (int jt = 0; jt < 2; ++jt)
                #pragma unroll
                for (int g = 0; g < 4; ++g) {
                    const int b = g*4;
                    C[it][jt][b+0] = __builtin_amdgcn_exp2f(C[it][jt][b+0]);
                    C[it][jt][b+1] = __builtin_amdgcn_exp2f(C[it][jt][b+1]);
                    C[it][jt][b+2] = __builtin_amdgcn_exp2f(C[it][jt][b+2]);
                    C[it][jt][b+3] = __builtin_amdgcn_exp2f(C[it][jt][b+3]);
                    t[jt*4+g] = (C[it][jt][b+0]+C[it][jt][b+1])
                              + (C[it][jt][b+2]+C[it][jt][b+3]);
                }
            const float sum = ((t[0]+t[1])+(t[2]+t[3])) + ((t[4]+t[5])+(t[6]+t[7]));
            const float tot = sum + __shfl_xor(sum, 32, 64);
            const float iv  = __builtin_amdgcn_rcpf(tot);

            // pack normalized P pairs -> this lane's sP row (R12 swizzle)
            #pragma unroll
            for (int jt = 0; jt < 2; ++jt)
                #pragma unroll
                for (int G = 0; G < 4; ++G) {
                    uint2 u;
                    u.x = cvt_pk_bf16(C[it][jt][4*G+0]*iv, C[it][jt][4*G+1]*iv);
                    u.y = cvt_pk_bf16(C[it][jt][4*G+2]*iv, C[it][jt][4*G+3]*iv);
                    const int j0 = jt*32 + 8*G + hi4;
                    *(uint2*)&pw[(((j0>>3) ^ (il&7))<<3) + (j0&7)] = u;
                }

            // PV: 16x16x32, A = P rows (b128), B = vf. Two independent chains.
            f32x4 O[2]; O[0] = 0; O[1] = 0;
            #pragma unroll
            for (int pit = 0; pit < 2; ++pit)
                #pragma unroll
                for (int kt = 0; kt < 2; ++kt) {
                    const int i = pit*16 + lr;
                    const bf16x8 pf = *(const bf16x8*)&sP[(wv*32+i)*64
                                      + (((kt*4+lg) ^ (i&7))<<3)];
                    O[pit] = __builtin_amdgcn_mfma_f32_16x16x32_bf16(pf, vf[kt],
                                                                     O[pit], 0,0,0);
                }

            // immediate store: lane col c = lr (<8), rows i = it*32+pit*16+lg*4+r
            if (lr < 8) {
                #pragma unroll
                for (int pit = 0; pit < 2; ++pit) {
                    float* ob = out + (size_t)w*4096
                              + (size_t)(it*32 + pit*16 + lg*4)*64 + h*8 + lr;
                    ob[0]   = O[pit][0];
                    ob[64]  = O[pit][1];
                    ob[128] = O[pit][2];
                    ob[192] = O[pit][3];
                }
            }
        }
    }
}

extern "C" void kernel_launch(void* const* d_in, const int* in_sizes, int n_in,
                              void* d_out, int out_size, void* d_ws, size_t ws_size,
                              hipStream_t stream)
{
    const float* x   = (const float*)d_in[0];
    const float* Wq  = (const float*)d_in[1];
    const float* bq  = (const float*)d_in[2];
    const float* pos = (const float*)d_in[3];
    float* out = (float*)d_out;
    unsigned short* pp = (unsigned short*)d_ws;   // 64 KB

    hipLaunchKernelGGL(prep_pos, dim3(128), dim3(256), 0, stream, pos, pp);
    hipLaunchKernelGGL(lm_mfma, dim3(8192), dim3(256), 0, stream, x, Wq, bq, pp, out);
}